// Round 4
// baseline (255.634 us; speedup 1.0000x reference)
//
#include <hip/hip_runtime.h>
#include <hip/hip_bf16.h>

#define B_   32
#define C_   64
#define H_   96
#define W_   96
#define K_   32
#define R_   13
#define HO_  84
#define WO_  84
#define HW_  (H_*W_)      // 9216
#define OHW_ (HO_*WO_)    // 7056
#define CRR_ (C_*R_*R_)   // 10816
#define RR_  (R_*R_)      // 169

#define TILE_ 16
#define PW_   28          // patch height/width = TILE_+12
#define NPIX_ (PW_*PW_)   // 784
#define REGB_ (NPIX_*16)  // 12544 bytes: one ks-half region (8ch/pixel), pixel-major
#define IMGS_ (2*REGB_)   // 25088 per image (16 ch of this pass)
#define LDS_BYTES (2*IMGS_) // 50176: two images

typedef unsigned int u32;
typedef unsigned short u16;
typedef __attribute__((ext_vector_type(16))) float f32x16;
typedef __attribute__((ext_vector_type(4))) u32 u32x4;

static __device__ __forceinline__ u16 f2bf(float v){
    __hip_bfloat16 h = __float2bfloat16(v);  // RNE
    return *reinterpret_cast<u16*>(&h);
}

// D = A*B + D  (32x32x16 bf16)
#define MFMA(acc, a, b) asm("v_mfma_f32_32x32x16_bf16 %0, %1, %2, %0" \
                            : "+v"(acc) : "v"(a), "v"(b))

// ---------------- k1: y-norms + bf16 prototype tensor ----------------------
// u_g layout: [pass(4)][jx(13)][i(13)] slices of 1KB; within slice:
// byte = k*32 + ks*16 + e*2  where element e of half ks = channel cbase+ks*8+e.
// Matches A-frag: lane(kpr,ks) reads 16B at slice + kpr*32 + ks*16.
__global__ void k_prep_y(const float* __restrict__ y, unsigned char* __restrict__ u_g){
    int k = blockIdx.x, tid = threadIdx.x;
    const float* yk = y + (size_t)k * CRR_;
    float ss = 0.f;
    for (int idx = tid; idx < CRR_; idx += 256){ float v = yk[idx]; ss += v*v; }
    for (int off = 32; off; off >>= 1) ss += __shfl_down(ss, off);
    __shared__ float red[4];
    if ((tid & 63) == 0) red[tid >> 6] = ss;
    __syncthreads();
    float inv = 1.f / fmaxf(sqrtf(red[0]+red[1]+red[2]+red[3]), 1e-9f);

    int c = tid & 63, grp = tid >> 6;                 // 64 c-lanes x 4 ij-groups
    int inoff = (k << 5) | ((c & 15) << 1);           // k*32 + (ks*8+e)*2
    for (int base = 0; base < RR_; base += 4){
        int ij = base + grp;
        if (ij < RR_){
            int i = ij / R_, jx = ij % R_;
            float v = yk[c*RR_ + ij] * inv;
            size_t slice = ((size_t)(c >> 4) * RR_ + jx*R_ + i) << 10;
            *(u16*)(u_g + slice + inoff) = f2bf(v);
        }
    }
}

// ---------------- k2: s[b,y,x] = sum_c x^2 (fp32 exact) --------------------
__global__ void k_sq(const float* __restrict__ x, float* __restrict__ s){
    int idx = blockIdx.x*256 + threadIdx.x;           // < 294912 exact
    int b = idx / HW_, r = idx % HW_;
    const float* xb = x + (size_t)b * C_ * HW_;
    float acc = 0.f;
    #pragma unroll
    for (int c = 0; c < C_; ++c){ float v = xb[(size_t)c*HW_ + r]; acc += v*v; }
    s[idx] = acc;
}

// ---------------- k3: inv_xn = 1/max(sqrt(13x13 box sum), eps) -------------
__global__ void k_inv(const float* __restrict__ s, float* __restrict__ inv_xn){
    int idx = blockIdx.x*256 + threadIdx.x;           // < 225792 exact
    int b = idx / OHW_, r = idx % OHW_;
    int oh = r / WO_, ow = r % WO_;
    const float* sb = s + (size_t)b*HW_ + oh*W_ + ow;
    float acc = 0.f;
    for (int i = 0; i < R_; ++i){
        #pragma unroll
        for (int j = 0; j < R_; ++j) acc += sb[i*W_ + j];
    }
    inv_xn[idx] = 1.f / fmaxf(sqrtf(acc), 1e-9f);
}

// ---------------- k_main: fused cosine-similarity conv ---------------------
// Block: 2 images x (16x16 tile), 256 thr (4 waves), 4 channel-passes (16ch).
// Wave owns rows 4wv+rb+{0,2} per image (2 frags). jx outer / i inner with a
// 3-deep rolling D-register window: B_frag1(i)=D(i+2) -> 15 LDS reads per jx
// per image instead of 26. A (y tap slice) loaded once per tap, shared by
// both images (4 MFMAs per A-load), prefetched 1 tap ahead (linear layout).
__launch_bounds__(256, 3)
__global__ void k_main(const float* __restrict__ x, const unsigned char* __restrict__ u_g,
                       const float* __restrict__ inv_xn, float* __restrict__ out){
    extern __shared__ unsigned char lds[];

    int bb   = blockIdx.x;
    int pair = bb / 36;
    int tt   = bb % 36;
    int oy = (tt / 6) * TILE_;
    int ox = (tt % 6) * TILE_;
    int b0 = pair * 2;

    int tid  = threadIdx.x;
    int lane = tid & 63;
    int wv   = tid >> 6;        // 0..3
    int ks   = lane >> 5;       // k-half of MFMA operands
    int rb   = (lane >> 4) & 1; // row within a frag's 2-row strip
    int cx   = lane & 15;       // col
    int kpr  = lane & 31;       // prototype row for A-frag

    const float* xb0 = x + (size_t)b0 * C_ * HW_;
    int aoff = (kpr << 5) + (ks << 4);      // A lane offset within 1KB slice
    int pb   = (4*wv + rb) * PW_ + cx;      // frag0 base pixel (row-offset 0)

    f32x16 aA0 = {}, aA1 = {}, aB0 = {}, aB1 = {};  // acc[img][frag]

    for (int pass = 0; pass < 4; ++pass){
        if (pass) __syncthreads();          // prior-pass reads done
        int cbase = pass << 4;
        // ---- stage 16 channels of both images: fp32 -> bf16, pixel-major ----
        for (int idx = tid; idx < 2*NPIX_; idx += 256){
            int img = (idx >= NPIX_);
            int p = idx - img*NPIX_;
            int py = p / PW_, px = p % PW_;
            int gy = oy + py; if (gy > H_-1) gy = H_-1;  // clamp feeds only invalid outputs
            int gx = ox + px; if (gx > W_-1) gx = W_-1;
            const float* src = xb0 + (size_t)img*C_*HW_ + (size_t)cbase*HW_ + gy*W_ + gx;
            u32 w0 = f2bf(src[0*HW_])  | ((u32)f2bf(src[1*HW_])  << 16);
            u32 w1 = f2bf(src[2*HW_])  | ((u32)f2bf(src[3*HW_])  << 16);
            u32 w2 = f2bf(src[4*HW_])  | ((u32)f2bf(src[5*HW_])  << 16);
            u32 w3 = f2bf(src[6*HW_])  | ((u32)f2bf(src[7*HW_])  << 16);
            u32x4 q0 = {w0, w1, w2, w3};
            u32 v0 = f2bf(src[8*HW_])  | ((u32)f2bf(src[9*HW_])  << 16);
            u32 v1 = f2bf(src[10*HW_]) | ((u32)f2bf(src[11*HW_]) << 16);
            u32 v2 = f2bf(src[12*HW_]) | ((u32)f2bf(src[13*HW_]) << 16);
            u32 v3 = f2bf(src[14*HW_]) | ((u32)f2bf(src[15*HW_]) << 16);
            u32x4 q1 = {v0, v1, v2, v3};
            *(u32x4*)(lds + img*IMGS_         + p*16) = q0;
            *(u32x4*)(lds + img*IMGS_ + REGB_ + p*16) = q1;
        }
        __syncthreads();

        const unsigned char* x0 = lds + ks*REGB_;           // img0, lane's k-half
        const unsigned char* x1 = lds + IMGS_ + ks*REGB_;   // img1
        const unsigned char* ug = u_g + ((size_t)pass*RR_ << 10);

        u32x4 A = *(const u32x4*)(ug + aoff);               // tap t=0
        int t = 0;
        for (int jx = 0; jx < R_; ++jx){
            int p0 = (pb + jx) * 16;
            // 3-deep D window (rows i, i+1, i+2)
            u32x4 d0a = *(const u32x4*)(x0 + p0);
            u32x4 d0b = *(const u32x4*)(x1 + p0);
            u32x4 d1a = *(const u32x4*)(x0 + p0 + PW_*16);
            u32x4 d1b = *(const u32x4*)(x1 + p0 + PW_*16);
            u32x4 d2a = *(const u32x4*)(x0 + p0 + 2*PW_*16);
            u32x4 d2b = *(const u32x4*)(x1 + p0 + 2*PW_*16);
            #pragma unroll
            for (int i = 0; i < R_; ++i, ++t){
                int tn = (t < RR_-1) ? t+1 : RR_-1;
                u32x4 An = *(const u32x4*)(ug + ((size_t)tn << 10) + aoff);
                u32x4 dna = d2a, dnb = d2b;
                if (i < R_-1){                              // prefetch D(i+3)
                    int pn = p0 + (i+3)*PW_*16;
                    dna = *(const u32x4*)(x0 + pn);
                    dnb = *(const u32x4*)(x1 + pn);
                }
                MFMA(aA0, A, d0a);      // img0 frag0: B = D(i)
                MFMA(aA1, A, d2a);      // img0 frag1: B = D(i+2)
                MFMA(aB0, A, d0b);
                MFMA(aB1, A, d2b);
                A = An;
                d0a = d1a; d1a = d2a; d2a = dna;
                d0b = d1b; d1b = d2b; d2b = dnb;
            }
        }
    }

    // ---- epilogue: relu(num) * 1/||x_win||; D: col=lane&31,
    // row = (r&3) + 8*(r>>2) + 4*(lane>>5) ----
    int ow = ox + cx;
#define EPI(ACC, IMG, F) {                                                   \
        int oh = oy + 4*wv + rb + 2*(F);                                     \
        bool valid = (oh < HO_) && (ow < WO_);                               \
        float inv = 0.f;                                                     \
        if (valid) inv = inv_xn[(size_t)(b0+(IMG))*OHW_ + oh*WO_ + ow];      \
        float* ob = out + (size_t)(b0+(IMG))*K_*OHW_ + oh*WO_ + ow;          \
        _Pragma("unroll")                                                    \
        for (int r = 0; r < 16; ++r){                                        \
            int kp = (r & 3) + 8*(r >> 2) + 4*ks;                            \
            if (valid) ob[(size_t)kp*OHW_] = fmaxf(ACC[r], 0.f) * inv;       \
        }                                                                    \
    }
    EPI(aA0, 0, 0); EPI(aA1, 0, 1); EPI(aB0, 1, 0); EPI(aB1, 1, 1);
#undef EPI
}

extern "C" void kernel_launch(void* const* d_in, const int* in_sizes, int n_in,
                              void* d_out, int out_size, void* d_ws, size_t ws_size,
                              hipStream_t stream) {
    const float* x = (const float*)d_in[0];
    const float* y = (const float*)d_in[1];
    float* out = (float*)d_out;
    unsigned char* ws = (unsigned char*)d_ws;

    unsigned char* u_g   = ws;                                   // 692224 B
    float*         s     = (float*)(ws + 692224);                // 1179648 B
    float*         invxn = (float*)(ws + 692224 + 1179648);      // 903168 B

    k_prep_y<<<K_, 256, 0, stream>>>(y, u_g);
    k_sq<<<(B_*HW_)/256, 256, 0, stream>>>(x, s);
    k_inv<<<(B_*OHW_)/256, 256, 0, stream>>>(s, invxn);

    k_main<<<(B_/2)*36, 256, LDS_BYTES, stream>>>(x, u_g, invxn, out);
}